// Round 2
// baseline (953.587 us; speedup 1.0000x reference)
//
#include <hip/hip_runtime.h>
#include <stdint.h>
#include <stddef.h>

// ---------------------------------------------------------------------------
// BayesianDTW forward on MI355X.
// Decomposition: 256 wgs = 32 batches x 8 column-stripes (128 cols each).
// Each wg = ONE wave (64 lanes, 2 cols/lane), lane-skewed systolic wavefront:
//   at step t, lane l computes DP row r = t - l for its 2 columns.
// Inter-stripe pipeline: producer flushes completed rows to d_out (coalesced),
// publishes a tagged flag in d_ws (agent-scope release); consumer spins
// (acquire) and reads its left-edge column from d_out. Stripe s only ever
// waits on stripe s-1 (lower blockIdx, dispatched earlier) -> deadlock-free.
// W staged global->LDS ring via global_load_lds; outputs staged in LDS ring,
// flushed as full rows. All mu math in log2 units; convert by ln2 on store.
// ---------------------------------------------------------------------------

#define NBATCH  32
#define NA      512          // DP rows (i = 1..512)
#define NB      1024         // DP cols (j = 1..1024)
#define NSTRIPE 8
#define SW      128          // cols per stripe
#define CH      16           // rows per chunk (flag/staging granularity)
#define NCHUNK  (NA / CH)    // 32
#define RING    128          // LDS ring rows (power of 2, >= 63 skew + 2*CH)
#define OROWS   513
#define OCOLS   1025

#define NEGV    (-1e20f)
#define LOG2E   (1.4426950408889634f)
#define LN2     (0.6931471805599453f)
#define NEG2    (-1.4426950408889634e20f)   // NEGV in log2 units
#define FLAGTAG 0x5A000000u                 // distinct from 0xAA poison

// v_exp_f32: 2^x ; v_log_f32: log2(x) — raw HW transcendentals
#define EXP2F(x) __builtin_amdgcn_exp2f(x)
#define LOG2F(x) __builtin_amdgcn_logf(x)

__device__ __forceinline__ void gl_lds(const float* g, float* l) {
    // async global->LDS DMA, 4B/lane, LDS dest = uniform base + lane*4
    __builtin_amdgcn_global_load_lds(
        (const __attribute__((address_space(1))) void*)g,
        (__attribute__((address_space(3))) void*)l, 4, 0, 0);
}

__device__ __forceinline__ float lse3_2(float a, float b, float c) {
    // log2(2^a + 2^b + 2^c); inputs/outputs in log2 units
    float m = fmaxf(fmaxf(a, b), c);           // v_max3_f32
    float s = EXP2F(a - m) + EXP2F(b - m) + EXP2F(c - m);
    return m + LOG2F(s);
}

__device__ __forceinline__ void wait_flag(unsigned int* fp, unsigned int need) {
    // spin until tagged counter >= need; bounded so a bug fails, not hangs
    for (int k = 0; k < (1 << 22); ++k) {
        unsigned int v = __hip_atomic_load(fp, __ATOMIC_ACQUIRE,
                                           __HIP_MEMORY_SCOPE_AGENT);
        if ((v >> 24) == 0x5Au && (v & 0x00FFFFFFu) >= need) return;
    }
}

__global__ __launch_bounds__(64, 1)
void dtw_pipe(const float* __restrict__ W, float* __restrict__ out,
              unsigned int* __restrict__ flags)
{
    __shared__ float lds_w[RING * SW];   // 64 KB: W ring (row r at slot r&127)
    __shared__ float lds_o[RING * SW];   // 64 KB: output ring (ln units)

    const int lane = (int)threadIdx.x;            // 0..63
    const int bid  = (int)blockIdx.x;             // s*32 + b (same-batch on one XCD)
    const int b    = bid & (NBATCH - 1);
    const int s    = bid >> 5;

    const float*  Wb  = W + ((size_t)b * NA) * NB + s * SW;  // row stride NB
    float*        ob  = out + (size_t)b * OROWS * OCOLS;     // row stride OCOLS
    unsigned int* fmy = flags + bid;
    unsigned int* fup = flags + (bid - NBATCH);              // producer stripe s-1

    // ---- boundary cells of output ----
    ob[s * SW + 1 + lane]      = NEGV;            // row 0, cols [128s+1 .. 128s+128]
    ob[s * SW + 1 + 64 + lane] = NEGV;
    if (s == 0) {
        if (lane == 0) ob[0] = 0.0f;              // mu[0,0] = 0
        for (int r = lane; r < NA; r += 64)
            ob[(size_t)(r + 1) * OCOLS] = NEGV;   // col 0 = NEG
    }

    // ---- prestage W chunks 0..2 (rows 0..47) ----
    for (int q = 0; q < 3; ++q) {
        const float* wsrc = Wb + (size_t)q * CH * NB;
        for (int rr = 0; rr < CH; ++rr) {
            const int slot = (q * CH + rr) & (RING - 1);
            gl_lds(wsrc + (size_t)rr * NB + lane,      &lds_w[slot * SW]);
            gl_lds(wsrc + (size_t)rr * NB + 64 + lane, &lds_w[slot * SW + 64]);
        }
    }

    // ---- consumer: prefetch edge chunks 0,1 (left column = mu[:, 128s]) ----
    float evcur = NEG2, evnxt = NEG2;             // lane rr<16 holds edge row 16c+1+rr
    if (s > 0) {
        wait_flag(fup, 1u);
        if (lane < CH)
            evcur = ob[(size_t)(1 + lane) * OCOLS + s * SW] * LOG2E;
        wait_flag(fup, 2u);
        if (lane < CH)
            evnxt = ob[(size_t)(CH + 1 + lane) * OCOLS + s * SW] * LOG2E;
    }

    asm volatile("s_waitcnt vmcnt(0)" ::: "memory");   // W chunks 0..2 + edges in

    // ---- systolic state (log2 units) ----
    float topA   = NEG2, topB = NEG2;     // mu[i-1, jA], mu[i-1, jB] (own columns)
    float sh_in  = NEG2;                  // mu[i, jA-1] from lane-1 (prev step)
    float tl_reg = NEG2;                  // mu[i-1, jA-1] (prev step's sh_in)
    float ev_im1 = (s == 0) ? 0.0f : NEG2;  // lane0 topleft: mu[0, 128s] (0 iff s==0)

    // W row for current step (row r = t - lane); preload row 0 (lane 0 only real)
    float2 w_cur = *(const float2*)&lds_w[(((0 - lane) & (RING - 1)) * SW) + 2 * lane];

    for (int t = 0; t < NA + 63; ++t) {            // 575 systolic steps
        const int r = t - lane;                    // DP row (mu row i = r+1)
        // prefetch next W row (off critical chain)
        float2 w_nxt = *(const float2*)
            &lds_w[(((r + 1) & (RING - 1)) * SW) + 2 * lane];
        // lane0 edge value for current row (uniform broadcast)
        const float ev_i = __shfl(evcur, t & (CH - 1));
        const float lf = (lane == 0) ? ev_i   : sh_in;    // mu[i, jA-1]
        const float tl = (lane == 0) ? ev_im1 : tl_reg;   // mu[i-1, jA-1]
        float uA = fmaf(w_cur.x, LOG2E, lse3_2(topA, lf, tl));
        float uB = fmaf(w_cur.y, LOG2E, lse3_2(topB, uA, topA));
        if (r >= 0 && r < NA) {
            *(float2*)&lds_o[((r & (RING - 1)) * SW) + 2 * lane]
                = make_float2(uA * LN2, uB * LN2);         // store in ln units
            topA = uA; topB = uB;
        }
        tl_reg = (r >= 0) ? lf : NEG2;
        ev_im1 = ev_i;
        sh_in  = __shfl_up(uB, 1);
        w_cur  = w_nxt;

        if ((t & (CH - 1)) == (CH - 1)) {          // chunk boundary, m = t>>4 in 0..34
            const int m = t >> 4;
            // 1) flush output chunk f = m-4 (rows 16f..16f+15 all complete: skew=63)
            const int f = m - 4;
            if (f >= 0) {
                const int r0 = f * CH;
                for (int rr = 0; rr < CH; ++rr) {
                    const int rw = r0 + rr;
                    const float v0 = lds_o[((rw & (RING - 1)) * SW) + lane];
                    const float v1 = lds_o[((rw & (RING - 1)) * SW) + 64 + lane];
                    float* orow = ob + (size_t)(rw + 1) * OCOLS + s * SW + 1;
                    orow[lane]      = v0;          // coalesced 256B row segments
                    orow[64 + lane] = v1;
                }
                __threadfence();                    // make rows visible cross-XCD
                if (lane == 0)
                    __hip_atomic_store(fmy, FLAGTAG + (unsigned)(f + 1),
                                       __ATOMIC_RELEASE, __HIP_MEMORY_SCOPE_AGENT);
            }
            // 2) drain staging issued two boundaries ago (W chunk m+2, edges m+1)
            asm volatile("s_waitcnt vmcnt(0)" ::: "memory");
            // 3) rotate edge chunks; poll + prefetch edge chunk m+2
            evcur = evnxt;
            if (s > 0 && (m + 2) < NCHUNK) {
                wait_flag(fup, (unsigned)(m + 3));
                if (lane < CH)
                    evnxt = ob[(size_t)((m + 2) * CH + 1 + lane) * OCOLS + s * SW]
                            * LOG2E;
            }
            // 4) stage W chunk q = m+3 (read starting t = 16q-1, drained at m+2)
            const int q = m + 3;
            if (q < NCHUNK) {
                const float* wsrc = Wb + (size_t)q * CH * NB;
                for (int rr = 0; rr < CH; ++rr) {
                    const int slot = (q * CH + rr) & (RING - 1);
                    gl_lds(wsrc + (size_t)rr * NB + lane,      &lds_w[slot * SW]);
                    gl_lds(wsrc + (size_t)rr * NB + 64 + lane, &lds_w[slot * SW + 64]);
                }
            }
        }
    }

    // ---- epilogue: flush last chunk f = 31 (rows 496..511) ----
    {
        const int r0 = (NCHUNK - 1) * CH;
        for (int rr = 0; rr < CH; ++rr) {
            const int rw = r0 + rr;
            const float v0 = lds_o[((rw & (RING - 1)) * SW) + lane];
            const float v1 = lds_o[((rw & (RING - 1)) * SW) + 64 + lane];
            float* orow = ob + (size_t)(rw + 1) * OCOLS + s * SW + 1;
            orow[lane]      = v0;
            orow[64 + lane] = v1;
        }
        __threadfence();
        if (lane == 0)
            __hip_atomic_store(fmy, FLAGTAG + (unsigned)NCHUNK,
                               __ATOMIC_RELEASE, __HIP_MEMORY_SCOPE_AGENT);
    }
}

extern "C" void kernel_launch(void* const* d_in, const int* in_sizes, int n_in,
                              void* d_out, int out_size, void* d_ws, size_t ws_size,
                              hipStream_t stream) {
    const float*  W     = (const float*)d_in[0];
    float*        out   = (float*)d_out;
    unsigned int* flags = (unsigned int*)d_ws;   // 256 tagged progress counters
    (void)in_sizes; (void)n_in; (void)out_size; (void)ws_size;
    hipLaunchKernelGGL(dtw_pipe, dim3(NBATCH * NSTRIPE), dim3(64), 0, stream,
                       W, out, flags);
}

// Round 3
// 491.878 us; speedup vs baseline: 1.9387x; 1.9387x over previous
//
#include <hip/hip_runtime.h>
#include <stdint.h>
#include <stddef.h>

// ---------------------------------------------------------------------------
// BayesianDTW forward on MI355X.
// 256 wgs = 32 batches x 8 column-stripes (128 cols, 1 wave, 2 cols/lane,
// lane-skewed systolic wavefront). Inter-stripe pipeline via d_out + flags.
//
// R3 change: NO cache-maintenance ops anywhere (no acquire/release fences,
// no __threadfence). Cross-stripe data (the stripe's last column) is
// duplicated as RELAXED agent-scope atomic stores (cache-bypassing, visible
// at the coherence point regardless of XCD placement); consumer reads edges
// with relaxed agent atomic loads. Flags are relaxed agent atomics padded to
// 128B. Ordering: s_waitcnt vmcnt(0) between edge stores and flag store.
// ---------------------------------------------------------------------------

#define NBATCH  32
#define NA      512          // DP rows (i = 1..512)
#define NB      1024         // DP cols (j = 1..1024)
#define NSTRIPE 8
#define SW      128          // cols per stripe
#define CH      16           // rows per chunk (flag/staging granularity)
#define NCHUNK  (NA / CH)    // 32
#define RING    128          // LDS ring rows (>= 63 skew + 2*CH)
#define OROWS   513
#define OCOLS   1025
#define FSTRIDE 32           // flag padding: 32 uints = 128 B

#define NEGV    (-1e20f)
#define LOG2E   (1.4426950408889634f)
#define LN2     (0.6931471805599453f)
#define NEG2    (-1.4426950408889634e20f)   // NEGV in log2 units
#define FLAGTAG 0x5A000000u                 // distinct from 0xAA poison

// v_exp_f32: 2^x ; v_log_f32: log2(x) — raw HW transcendentals
#define EXP2F(x) __builtin_amdgcn_exp2f(x)
#define LOG2F(x) __builtin_amdgcn_logf(x)

__device__ __forceinline__ void gl_lds(const float* g, float* l) {
    // async global->LDS DMA, 4B/lane, LDS dest = uniform base + lane*4
    __builtin_amdgcn_global_load_lds(
        (const __attribute__((address_space(1))) void*)g,
        (__attribute__((address_space(3))) void*)l, 4, 0, 0);
}

__device__ __forceinline__ float lse3_2(float a, float b, float c) {
    // log2(2^a + 2^b + 2^c); inputs/outputs in log2 units
    float m = fmaxf(fmaxf(a, b), c);           // v_max3_f32
    float s = EXP2F(a - m) + EXP2F(b - m) + EXP2F(c - m);
    return m + LOG2F(s);
}

// relaxed agent-scope atomics: cache-bypassing access, NO buffer_inv/wbl2
__device__ __forceinline__ unsigned int ld_flag(unsigned int* fp) {
    return __hip_atomic_load(fp, __ATOMIC_RELAXED, __HIP_MEMORY_SCOPE_AGENT);
}
__device__ __forceinline__ void st_flag(unsigned int* fp, unsigned int v) {
    __hip_atomic_store(fp, v, __ATOMIC_RELAXED, __HIP_MEMORY_SCOPE_AGENT);
}
__device__ __forceinline__ float ld_edge(const float* p) {
    return __hip_atomic_load((float*)p, __ATOMIC_RELAXED,
                             __HIP_MEMORY_SCOPE_AGENT);
}
__device__ __forceinline__ void st_edge(float* p, float v) {
    __hip_atomic_store(p, v, __ATOMIC_RELAXED, __HIP_MEMORY_SCOPE_AGENT);
}

__device__ __forceinline__ void wait_flag(unsigned int* fp, unsigned int need) {
    // spin until tagged counter >= need; bounded so a bug fails, not hangs
    for (int k = 0; k < (1 << 22); ++k) {
        unsigned int v = ld_flag(fp);
        if ((v >> 24) == 0x5Au && (v & 0x00FFFFFFu) >= need) break;
    }
    asm volatile("" ::: "memory");   // no hoisting edge loads above the poll
}

__global__ __launch_bounds__(64, 1)
void dtw_pipe(const float* __restrict__ W, float* __restrict__ out,
              unsigned int* __restrict__ flags)
{
    __shared__ float lds_w[RING * SW];   // 64 KB: W ring (row r at slot r&127)
    __shared__ float lds_o[RING * SW];   // 64 KB: output ring (ln units)

    const int lane = (int)threadIdx.x;            // 0..63
    const int bid  = (int)blockIdx.x;             // s*32 + b
    const int b    = bid & (NBATCH - 1);
    const int s    = bid >> 5;

    const float*  Wb  = W + ((size_t)b * NA) * NB + s * SW;  // row stride NB
    float*        ob  = out + (size_t)b * OROWS * OCOLS;     // row stride OCOLS
    unsigned int* fmy = flags + (size_t)bid * FSTRIDE;
    unsigned int* fup = flags + (size_t)(bid - NBATCH) * FSTRIDE;

    // ---- boundary cells of output ----
    ob[s * SW + 1 + lane]      = NEGV;            // row 0, cols [128s+1 .. 128s+128]
    ob[s * SW + 1 + 64 + lane] = NEGV;
    if (s == 0) {
        if (lane == 0) ob[0] = 0.0f;              // mu[0,0] = 0
        for (int r = lane; r < NA; r += 64)
            ob[(size_t)(r + 1) * OCOLS] = NEGV;   // col 0 = NEG
    }

    // ---- prestage W chunks 0..2 (rows 0..47) ----
    for (int q = 0; q < 3; ++q) {
        const float* wsrc = Wb + (size_t)q * CH * NB;
        for (int rr = 0; rr < CH; ++rr) {
            const int slot = (q * CH + rr) & (RING - 1);
            gl_lds(wsrc + (size_t)rr * NB + lane,      &lds_w[slot * SW]);
            gl_lds(wsrc + (size_t)rr * NB + 64 + lane, &lds_w[slot * SW + 64]);
        }
    }

    // ---- consumer: prefetch edge chunks 0,1 (left column = mu[:, 128s]) ----
    float evcur = NEG2, evnxt = NEG2;             // lane rr<16 holds edge row 16c+1+rr
    if (s > 0) {
        wait_flag(fup, 1u);
        if (lane < CH)
            evcur = ld_edge(&ob[(size_t)(1 + lane) * OCOLS + s * SW]) * LOG2E;
        wait_flag(fup, 2u);
        if (lane < CH)
            evnxt = ld_edge(&ob[(size_t)(CH + 1 + lane) * OCOLS + s * SW]) * LOG2E;
    }

    asm volatile("s_waitcnt vmcnt(0)" ::: "memory");   // W chunks 0..2 + edges in

    // ---- systolic state (log2 units) ----
    float topA   = NEG2, topB = NEG2;     // mu[i-1, jA], mu[i-1, jB] (own columns)
    float sh_in  = NEG2;                  // mu[i, jA-1] from lane-1 (prev step)
    float tl_reg = NEG2;                  // mu[i-1, jA-1] (prev step's sh_in)
    float ev_im1 = (s == 0) ? 0.0f : NEG2;  // lane0 topleft: mu[0, 128s]

    // W row for current step (row r = t - lane); preload row 0
    float2 w_cur = *(const float2*)&lds_w[(((0 - lane) & (RING - 1)) * SW) + 2 * lane];

    for (int t = 0; t < NA + 63; ++t) {            // 575 systolic steps
        const int r = t - lane;                    // DP row (mu row i = r+1)
        // prefetch next W row (off critical chain)
        float2 w_nxt = *(const float2*)
            &lds_w[(((r + 1) & (RING - 1)) * SW) + 2 * lane];
        // lane0 edge value for current row (uniform broadcast)
        const float ev_i = __shfl(evcur, t & (CH - 1));
        const float lf = (lane == 0) ? ev_i   : sh_in;    // mu[i, jA-1]
        const float tl = (lane == 0) ? ev_im1 : tl_reg;   // mu[i-1, jA-1]
        float uA = fmaf(w_cur.x, LOG2E, lse3_2(topA, lf, tl));
        float uB = fmaf(w_cur.y, LOG2E, lse3_2(topB, uA, topA));
        if (r >= 0 && r < NA) {
            *(float2*)&lds_o[((r & (RING - 1)) * SW) + 2 * lane]
                = make_float2(uA * LN2, uB * LN2);         // store in ln units
            topA = uA; topB = uB;
        }
        tl_reg = (r >= 0) ? lf : NEG2;
        ev_im1 = ev_i;
        sh_in  = __shfl_up(uB, 1);
        w_cur  = w_nxt;

        if ((t & (CH - 1)) == (CH - 1)) {          // chunk boundary, m = t>>4
            const int m = t >> 4;
            // 1) flush output chunk f = m-4 (rows all complete: skew=63)
            const int f = m - 4;
            if (f >= 0) {
                const int r0 = f * CH;
                for (int rr = 0; rr < CH; ++rr) {
                    const int rw = r0 + rr;
                    const float v0 = lds_o[((rw & (RING - 1)) * SW) + lane];
                    const float v1 = lds_o[((rw & (RING - 1)) * SW) + 64 + lane];
                    float* orow = ob + (size_t)(rw + 1) * OCOLS + s * SW + 1;
                    orow[lane]      = v0;          // coalesced 256B row segments
                    orow[64 + lane] = v1;
                }
                // duplicate edge column (local col 127 = global col 128(s+1))
                // as cache-bypassing stores -> visible at coherence point
                if (s < NSTRIPE - 1 && lane < CH) {
                    const int rw = r0 + lane;
                    const float ev = lds_o[((rw & (RING - 1)) * SW) + SW - 1];
                    st_edge(ob + (size_t)(rw + 1) * OCOLS + (s + 1) * SW, ev);
                }
                // order: all stores (incl. edge) complete before flag publish
                asm volatile("s_waitcnt vmcnt(0)" ::: "memory");
                if (s < NSTRIPE - 1 && lane == 0)
                    st_flag(fmy, FLAGTAG + (unsigned)(f + 1));
            } else {
                asm volatile("s_waitcnt vmcnt(0)" ::: "memory"); // drain staging
            }
            // 2) rotate edge chunks; poll + prefetch edge chunk m+2
            evcur = evnxt;
            if (s > 0 && (m + 2) < NCHUNK) {
                wait_flag(fup, (unsigned)(m + 3));
                if (lane < CH)
                    evnxt = ld_edge(&ob[(size_t)((m + 2) * CH + 1 + lane) * OCOLS
                                        + s * SW]) * LOG2E;
            }
            // 3) stage W chunk q = m+3 (first used at t = 16q, drained m+1/m+2)
            const int q = m + 3;
            if (q < NCHUNK) {
                const float* wsrc = Wb + (size_t)q * CH * NB;
                for (int rr = 0; rr < CH; ++rr) {
                    const int slot = (q * CH + rr) & (RING - 1);
                    gl_lds(wsrc + (size_t)rr * NB + lane,      &lds_w[slot * SW]);
                    gl_lds(wsrc + (size_t)rr * NB + 64 + lane, &lds_w[slot * SW + 64]);
                }
            }
        }
    }

    // ---- epilogue: flush last chunk f = 31 (rows 496..511) ----
    {
        const int r0 = (NCHUNK - 1) * CH;
        for (int rr = 0; rr < CH; ++rr) {
            const int rw = r0 + rr;
            const float v0 = lds_o[((rw & (RING - 1)) * SW) + lane];
            const float v1 = lds_o[((rw & (RING - 1)) * SW) + 64 + lane];
            float* orow = ob + (size_t)(rw + 1) * OCOLS + s * SW + 1;
            orow[lane]      = v0;
            orow[64 + lane] = v1;
        }
        if (s < NSTRIPE - 1 && lane < CH) {
            const int rw = r0 + lane;
            const float ev = lds_o[((rw & (RING - 1)) * SW) + SW - 1];
            st_edge(ob + (size_t)(rw + 1) * OCOLS + (s + 1) * SW, ev);
        }
        asm volatile("s_waitcnt vmcnt(0)" ::: "memory");
        if (s < NSTRIPE - 1 && lane == 0)
            st_flag(fmy, FLAGTAG + (unsigned)NCHUNK);
    }
}

extern "C" void kernel_launch(void* const* d_in, const int* in_sizes, int n_in,
                              void* d_out, int out_size, void* d_ws, size_t ws_size,
                              hipStream_t stream) {
    const float*  W     = (const float*)d_in[0];
    float*        out   = (float*)d_out;
    unsigned int* flags = (unsigned int*)d_ws;   // 256 padded tagged counters
    (void)in_sizes; (void)n_in; (void)out_size; (void)ws_size;
    hipLaunchKernelGGL(dtw_pipe, dim3(NBATCH * NSTRIPE), dim3(64), 0, stream,
                       W, out, flags);
}

// Round 7
// 414.308 us; speedup vs baseline: 2.3016x; 1.1872x over previous
//
#include <hip/hip_runtime.h>
#include <stdint.h>
#include <stddef.h>

// ---------------------------------------------------------------------------
// BayesianDTW forward on MI355X — R7.
// 256 wgs = 32 batches x 8 column-stripes (128 cols, 1 wave, 2 cols/lane,
// lane-skewed systolic wavefront; lane l computes DP row r = t - l).
// Math: R3-PROVEN log2-domain lse3 recurrence (passed absmax 8.0).
// R7 changes vs R3 (all off the proven math):
//   - systolic pass: DPP row_shr:1 (+readlane patches for lanes 16/32/48)
//     instead of ds_bpermute __shfl_up  (~15cy vs ~120cy, on carried chain)
//   - edge broadcast: v_readlane with immediate (unrolled tt) instead of
//     __shfl(evcur, t&15)  (removes 2nd LDS op from the loop)
//   - R6 protocol: hidden flag poll at tt==1, delayed flag publish under
//     s_waitcnt vmcnt(1) (no uncached-store drain on critical path),
//     3-deep edge prefetch (lres), W-ring prefetch 2 steps ahead
//   - LDS strides back to 128 (skewed row access banks = 2l mod 32: benign)
// ---------------------------------------------------------------------------

#define NBATCH  32
#define NA      512
#define NB      1024
#define NSTRIPE 8
#define SW      128          // cols per stripe
#define CH      16           // rows per chunk
#define NCHUNK  (NA / CH)    // 32
#define LSTR    128          // LDS row stride (floats)
#define OROWS   513
#define OCOLS   1025
#define FSTRIDE 32           // flag padding: 128 B

#define NEGV    (-1e20f)
#define LOG2E   (1.4426950408889634f)
#define LN2     (0.6931471805599453f)
#define NEG2    (-1.4426950408889634e20f)   // NEGV in log2 units
#define FLAGTAG 0x5A000000u

#define EXP2F(x) __builtin_amdgcn_exp2f(x)   // v_exp_f32: 2^x
#define LOG2F(x) __builtin_amdgcn_logf(x)    // v_log_f32: log2(x)

__device__ __forceinline__ void gl_lds(const float* g, float* l) {
    __builtin_amdgcn_global_load_lds(
        (const __attribute__((address_space(1))) void*)g,
        (__attribute__((address_space(3))) void*)l, 4, 0, 0);
}

__device__ __forceinline__ float lse3_2(float a, float b, float c) {
    // log2(2^a + 2^b + 2^c); inputs/outputs in log2 units. NaN-free for
    // finite inputs (diffs <= 0, exp2 in [0,1], sum in [1,3]).
    float m = fmaxf(fmaxf(a, b), c);           // v_max3_f32
    float s = EXP2F(a - m) + EXP2F(b - m) + EXP2F(c - m);
    return m + LOG2F(s);
}

__device__ __forceinline__ float rdlane(float v, int l) {
    return __int_as_float(__builtin_amdgcn_readlane(__float_as_int(v), l));
}

// lane i <- lane i-1 across the full wave, pure VALU:
// DPP row_shr:1 (16-lane rows) + readlane patches at lanes 16/32/48.
// Lane 0 result unused (edge path). R4's bug was WAVEFRONT mode 0x138;
// row_shr (0x111) is a supported CDNA DPP16 control.
__device__ __forceinline__ float lane_shr1(float x, int lane) {
    int xi  = __float_as_int(x);
    int shr = __builtin_amdgcn_update_dpp(0, xi, 0x111, 0xf, 0xf, true);
    float v = __int_as_float(shr);
    float a15 = rdlane(x, 15), a31 = rdlane(x, 31), a47 = rdlane(x, 47);
    v = (lane == 16) ? a15 : v;
    v = (lane == 32) ? a31 : v;
    v = (lane == 48) ? a47 : v;
    return v;
}

__device__ __forceinline__ unsigned int ld_flag(unsigned int* fp) {
    return __hip_atomic_load(fp, __ATOMIC_RELAXED, __HIP_MEMORY_SCOPE_AGENT);
}
__device__ __forceinline__ void st_flag(unsigned int* fp, unsigned int v) {
    __hip_atomic_store(fp, v, __ATOMIC_RELAXED, __HIP_MEMORY_SCOPE_AGENT);
}
__device__ __forceinline__ float ld_edge(const float* p) {
    return __hip_atomic_load((float*)p, __ATOMIC_RELAXED, __HIP_MEMORY_SCOPE_AGENT);
}
__device__ __forceinline__ void st_edge(float* p, float v) {
    __hip_atomic_store(p, v, __ATOMIC_RELAXED, __HIP_MEMORY_SCOPE_AGENT);
}

__device__ __forceinline__ void wait_flag(unsigned int* fp, unsigned int need) {
    for (int k = 0; k < (1 << 22); ++k) {
        unsigned int v = ld_flag(fp);
        if ((v >> 24) == 0x5Au && (v & 0x00FFFFFFu) >= need) break;
    }
    asm volatile("" ::: "memory");
}

__global__ __launch_bounds__(64, 1)
void dtw_pipe(const float* __restrict__ W, float* __restrict__ out,
              unsigned int* __restrict__ flags)
{
    __shared__ float lds_w[128 * LSTR];   // W ring: row r at slot r&127
    __shared__ float lds_o[128 * LSTR];   // output ring (ln units, final)

    const int lane = (int)threadIdx.x;
    const int bid  = (int)blockIdx.x;             // s*32 + b
    const int b    = bid & (NBATCH - 1);
    const int s    = bid >> 5;

    const float*  Wb  = W + ((size_t)b * NA) * NB + s * SW;
    float*        ob  = out + (size_t)b * OROWS * OCOLS;
    unsigned int* fmy = flags + (size_t)bid * FSTRIDE;
    unsigned int* fup = flags + (size_t)(bid - NBATCH) * FSTRIDE;

    // ---- boundary cells of output (final values; nobody reads these) ----
    ob[s * SW + 1 + lane]      = NEGV;
    ob[s * SW + 1 + 64 + lane] = NEGV;
    if (s == 0) {
        if (lane == 0) ob[0] = 0.0f;
        for (int r = lane; r < NA; r += 64)
            ob[(size_t)(r + 1) * OCOLS] = NEGV;
    }

    // ---- prestage W chunks 0..2 (rows 0..47) ----
    for (int q = 0; q < 3; ++q) {
        const float* wsrc = Wb + (size_t)q * CH * NB;
        for (int rr = 0; rr < CH; ++rr) {
            const int slot = q * CH + rr;
            gl_lds(wsrc + (size_t)rr * NB + lane,      &lds_w[slot * LSTR]);
            gl_lds(wsrc + (size_t)rr * NB + 64 + lane, &lds_w[slot * LSTR + 64]);
        }
    }

    // ---- edge prefetch (log2 units; lanes 0..15 hold 16 rows each) ----
    float evcur = -1e30f, evnxt = -1e30f, lres = -1e30f;
    if (s > 0) {
        wait_flag(fup, 1u);
        if (lane < CH)
            evcur = ld_edge(&ob[(size_t)(1 + lane) * OCOLS + s * SW]) * LOG2E;
        wait_flag(fup, 2u);
        if (lane < CH)
            evnxt = ld_edge(&ob[(size_t)(CH + 1 + lane) * OCOLS + s * SW]) * LOG2E;
        wait_flag(fup, 3u);
        if (lane < CH)
            lres  = ld_edge(&ob[(size_t)(2 * CH + 1 + lane) * OCOLS + s * SW]) * LOG2E;
    }

    asm volatile("s_waitcnt vmcnt(0)" ::: "memory");   // gl_lds + edges done

    // ---- systolic state (log2 units, R3-proven) ----
    float topA = NEG2, topB = NEG2;   // mu[i-1, jA], mu[i-1, jB] (log2)
    float sh_in = NEG2;               // left neighbor's uB from prev step
    float tl_reg = NEG2;              // mu[i-1, jA-1]
    float ev_im1 = (s == 0) ? 0.0f : NEG2;  // lane0 topleft: mu[0,128s]·log2e
    unsigned int fpoll = 0;

    // W prefetch: w_cur = row r(t), w_nx1 = row r(t)+1; issue +2 each step
    float2 w_cur = *(const float2*)&lds_w[((0 - lane) & 127) * LSTR + 2 * lane];
    float2 w_nx1 = *(const float2*)&lds_w[((1 - lane) & 127) * LSTR + 2 * lane];

    auto step = [&](int m_, int tt) {
        const int t = (m_ << 4) + tt;
        const int r = t - lane;
        if (tt == 1 && s > 0) fpoll = ld_flag(fup);      // hidden poll
        // prefetch W row r+2 (2-step lead > ds latency)
        float2 w_pre = *(const float2*)&lds_w[((r + 2) & 127) * LSTR + 2 * lane];
        // edge broadcast: wave-uniform immediate lane index -> v_readlane
        const float ev_i = rdlane(evcur, tt);
        // ---- carried chain ----
        const float lf = (lane == 0) ? ev_i   : sh_in;   // mu[i, jA-1]
        const float tl = (lane == 0) ? ev_im1 : tl_reg;  // mu[i-1, jA-1]
        const float uA = fmaf(w_cur.x, LOG2E, lse3_2(topA, lf, tl));
        const float uB = fmaf(w_cur.y, LOG2E, lse3_2(topB, uA, topA));
        const bool on = (r >= 0);
        if (on & (r < NA)) {                             // off-chain store (ln)
            *(float2*)&lds_o[(r & 127) * LSTR + 2 * lane]
                = make_float2(uA * LN2, uB * LN2);
        }
        topA   = on ? uA : NEG2;
        topB   = on ? uB : NEG2;
        tl_reg = on ? lf : NEG2;
        ev_im1 = ev_i;
        sh_in  = lane_shr1(uB, lane);                    // pure-VALU pass
        w_cur = w_nx1; w_nx1 = w_pre;
    };

    for (int m = 0; m < 35; ++m) {
        #pragma unroll
        for (int tt = 0; tt < 16; ++tt) step(m, tt);

        // ================= chunk boundary (t = 16m+15 done) =================
        const int f = m - 4;                  // chunk fully complete (skew 63)
        // 1) uncached edge-column dup for chunk f (acked by NEXT boundary)
        if (s < NSTRIPE - 1 && f >= 0 && lane < CH) {
            const int rw = (f << 4) + lane;
            const float evl = lds_o[(rw & 127) * LSTR + 127];
            st_edge(ob + (size_t)(rw + 1) * OCOLS + (s + 1) * SW, evl);
        }
        // 2) vmcnt(1): all but the just-issued edge store complete ->
        //    chunk f-1's edge stores visible; publish flag f (claims <= f-1).
        //    Also transitively guarantees W staging from boundary m-1 landed.
        asm volatile("s_waitcnt vmcnt(1)" ::: "memory");
        if (s < NSTRIPE - 1 && f >= 1 && lane == 0)
            st_flag(fmy, FLAGTAG + (unsigned)f);
        // 3) coalesced flush of chunk f
        if (f >= 0) {
            #pragma unroll
            for (int rr = 0; rr < CH; ++rr) {
                const int rw = (f << 4) + rr;
                const float v0 = lds_o[(rw & 127) * LSTR + lane];
                const float v1 = lds_o[(rw & 127) * LSTR + 64 + lane];
                float* orow = ob + (size_t)(rw + 1) * OCOLS + s * SW + 1;
                orow[lane]      = v0;
                orow[64 + lane] = v1;
            }
        }
        // 4) rotate edge regs; load chunk m+3 (need m+4, polled at tt==1)
        evcur = evnxt; evnxt = lres;
        const int c = m + 3;
        if (s > 0 && c < NCHUNK) {
            const unsigned need = (unsigned)(m + 4);
            if (!((fpoll >> 24) == 0x5Au && (fpoll & 0x00FFFFFFu) >= need))
                wait_flag(fup, need);
            lres = -1e30f;
            if (lane < CH)
                lres = ld_edge(&ob[(size_t)((c << 4) + 1 + lane) * OCOLS + s * SW])
                       * LOG2E;
        }
        // 5) stage W chunk m+3
        if (c < NCHUNK) {
            const float* wsrc = Wb + (size_t)(c << 4) * NB;
            #pragma unroll
            for (int rr = 0; rr < CH; ++rr) {
                const int slot = ((c << 4) + rr) & 127;
                gl_lds(wsrc + (size_t)rr * NB + lane,      &lds_w[slot * LSTR]);
                gl_lds(wsrc + (size_t)rr * NB + 64 + lane, &lds_w[slot * LSTR + 64]);
            }
        }
    }

    // tail steps t = 560..574 (lane 63 finishes row 511 at t=574)
    #pragma unroll
    for (int tt = 0; tt < 15; ++tt) step(35, tt);

    // ---- epilogue: chunk 31 ----
    {
        const int f = NCHUNK - 1;
        if (s < NSTRIPE - 1 && lane < CH) {
            const int rw = (f << 4) + lane;
            const float evl = lds_o[(rw & 127) * LSTR + 127];
            st_edge(ob + (size_t)(rw + 1) * OCOLS + (s + 1) * SW, evl);
        }
        asm volatile("s_waitcnt vmcnt(1)" ::: "memory");
        if (s < NSTRIPE - 1 && lane == 0)
            st_flag(fmy, FLAGTAG + (unsigned)(NCHUNK - 1));   // chunks 0..30
        #pragma unroll
        for (int rr = 0; rr < CH; ++rr) {
            const int rw = (f << 4) + rr;
            const float v0 = lds_o[(rw & 127) * LSTR + lane];
            const float v1 = lds_o[(rw & 127) * LSTR + 64 + lane];
            float* orow = ob + (size_t)(rw + 1) * OCOLS + s * SW + 1;
            orow[lane]      = v0;
            orow[64 + lane] = v1;
        }
        asm volatile("s_waitcnt vmcnt(0)" ::: "memory");
        if (s < NSTRIPE - 1 && lane == 0)
            st_flag(fmy, FLAGTAG + (unsigned)NCHUNK);         // all 32 chunks
    }
}

extern "C" void kernel_launch(void* const* d_in, const int* in_sizes, int n_in,
                              void* d_out, int out_size, void* d_ws, size_t ws_size,
                              hipStream_t stream) {
    const float*  W     = (const float*)d_in[0];
    float*        out   = (float*)d_out;
    unsigned int* flags = (unsigned int*)d_ws;
    (void)in_sizes; (void)n_in; (void)out_size; (void)ws_size;
    hipLaunchKernelGGL(dtw_pipe, dim3(NBATCH * NSTRIPE), dim3(64), 0, stream,
                       W, out, flags);
}